// Round 2
// baseline (1075.274 us; speedup 1.0000x reference)
//
#include <hip/hip_runtime.h>

#define BB 512
#define TT 1024
#define DX 32
#define DZ 64
#define DY 256
#define ALPHA 0.125f
#define HP 36  // hid chunk stride: 32 floats + 4 pad

// DPP add: x + dpp_permuted(x), VALU pipe only.
// 0xB1 = quad_perm xor1, 0x4E = quad_perm xor2, 0x141 = row_half_mirror
// (completes an 8-lane allreduce after xor1+xor2).
template<int CTRL>
__device__ __forceinline__ float dpp_add(float x) {
    int p = __builtin_amdgcn_update_dpp(0, __float_as_int(x), CTRL, 0xF, 0xF, true);
    return x + __int_as_float(p);
}

// TWO batch elements per block, 512 threads (8 waves), grid = 256 blocks (1/CU).
// The two recurrences are independent -> two interleaved instruction streams
// per wave hide LDS turnaround + DPP-chain latency, and the per-step fixed
// costs (2 barriers, loop control, prefetch) are paid once per 2 batch-steps.
// m1: thread (y=tid>>1, half=tid&1): hidden row y over z-chunk 32*half..+31,
//     for both batches; 1 DPP (xor1) completes each 64-z dot.
// m2: thread (z=tid>>3, oct=tid&7): latent row z over y-chunk 32*oct..+31,
//     for both batches; xor1+xor2+half_mirror completes each 256-y dot.
//     All 8 lanes of the oct-group replicate the state update (no extra
//     exec-mask for compute); oct==0 lane does the stores.
__global__ __launch_bounds__(512, 2)
void plrnn_scan(const float* __restrict__ X, const float* __restrict__ A,
                const float* __restrict__ W1, const float* __restrict__ W2,
                const float* __restrict__ h1, const float* __restrict__ h2,
                float* __restrict__ out) {
    const int bb  = blockIdx.x * 2;
    const int tid = threadIdx.x;

    const int y    = tid >> 1;      // m1 output row 0..255
    const int half = tid & 1;       // m1 z-chunk
    const int z    = tid >> 3;      // m2 output row 0..63
    const int oct  = tid & 7;       // m2 y-chunk
    const int wv   = tid >> 6;      // wave id 0..7

    __shared__ float zf_s[2][DZ];
    __shared__ float hid_s[2][8 * HP];

    // ---- one-time: weight tiles into registers (shared by both batches) ----
    float4 w2r[8];   // W2[y, 32*half + 4j .. +3]
    float4 w1r[8];   // W1[z, 32*oct  + 4j .. +3]
#pragma unroll
    for (int j = 0; j < 8; ++j) {
        w2r[j] = *(const float4*)&W2[y * DZ + 32 * half + 4 * j];
        w1r[j] = *(const float4*)&W1[z * DY + 32 * oct + 4 * j];
    }
    const float h2r = h2[y];
    const float Ar  = A[z];
    const float h1r = h1[z];
    const bool  zlt = (z < DX);

    const float* Xb0 = X   + (size_t)bb * TT * DX;
    const float* Xb1 = Xb0 + (size_t)TT * DX;
    float*       Ob0 = out + (size_t)bb * TT * DX;
    float*       Ob1 = Ob0 + (size_t)TT * DX;

    // ---- zf_0 = x0 (non-NaN) on first DX dims, else 0; replicated on all
    //      8 lanes of each oct-group ----
    float zf0 = 0.f, zf1 = 0.f;
    if (zlt) {
        float xa = Xb0[z], xb = Xb1[z];
        zf0 = (xa == xa) ? xa : 0.f;
        zf1 = (xb == xb) ? xb : 0.f;
    }
    if (oct == 0) { zf_s[0][z] = zf0; zf_s[1][z] = zf1; }
    __syncthreads();

    const int hidx = wv * HP + (y & 31);   // m1 write slot (half==0 lanes)
    const float* w2f = (const float*)w2r;
    const float* w1f = (const float*)w1r;

    for (int t = 0; t < TT; ++t) {
        // prefetch next forcing values (consumed at the m2 tail)
        float xn0 = 0.f, xn1 = 0.f;
        if (zlt && (t + 1) < TT) {
            xn0 = Xb0[(t + 1) * DX + z];
            xn1 = Xb1[(t + 1) * DX + z];
        }

        // ---- m1: hidden = relu(W2 @ zf + h2), both batches ----
        const float4* zp0 = (const float4*)(&zf_s[0][32 * half]);
        const float4* zp1 = (const float4*)(&zf_s[1][32 * half]);
        float a0 = 0.f, a1 = 0.f, a2 = 0.f, a3 = 0.f;
        float c0 = 0.f, c1 = 0.f, c2 = 0.f, c3 = 0.f;
#pragma unroll
        for (int j = 0; j < 8; ++j) {
            float4 va = zp0[j];
            float4 vb = zp1[j];
            a0 = fmaf(w2f[4 * j + 0], va.x, a0);
            a1 = fmaf(w2f[4 * j + 1], va.y, a1);
            a2 = fmaf(w2f[4 * j + 2], va.z, a2);
            a3 = fmaf(w2f[4 * j + 3], va.w, a3);
            c0 = fmaf(w2f[4 * j + 0], vb.x, c0);
            c1 = fmaf(w2f[4 * j + 1], vb.y, c1);
            c2 = fmaf(w2f[4 * j + 2], vb.z, c2);
            c3 = fmaf(w2f[4 * j + 3], vb.w, c3);
        }
        float d1a = (a0 + a1) + (a2 + a3);
        float d1b = (c0 + c1) + (c2 + c3);
        d1a = dpp_add<0xB1>(d1a);
        d1b = dpp_add<0xB1>(d1b);
        if (half == 0) {
            hid_s[0][hidx] = fmaxf(d1a + h2r, 0.0f);
            hid_s[1][hidx] = fmaxf(d1b + h2r, 0.0f);
        }
        __syncthreads();

        // ---- m2 + fused update: z_new = A*zf + W1 @ hidden + h1 ----
        const float4* hp0 = (const float4*)(&hid_s[0][HP * oct]);
        const float4* hp1 = (const float4*)(&hid_s[1][HP * oct]);
        float p0 = 0.f, p1 = 0.f, p2 = 0.f, p3 = 0.f;
        float q0 = 0.f, q1 = 0.f, q2 = 0.f, q3 = 0.f;
#pragma unroll
        for (int j = 0; j < 8; ++j) {
            float4 va = hp0[j];
            float4 vb = hp1[j];
            p0 = fmaf(w1f[4 * j + 0], va.x, p0);
            p1 = fmaf(w1f[4 * j + 1], va.y, p1);
            p2 = fmaf(w1f[4 * j + 2], va.z, p2);
            p3 = fmaf(w1f[4 * j + 3], va.w, p3);
            q0 = fmaf(w1f[4 * j + 0], vb.x, q0);
            q1 = fmaf(w1f[4 * j + 1], vb.y, q1);
            q2 = fmaf(w1f[4 * j + 2], vb.z, q2);
            q3 = fmaf(w1f[4 * j + 3], vb.w, q3);
        }
        float d2a = (p0 + p1) + (p2 + p3);
        float d2b = (q0 + q1) + (q2 + q3);
        d2a = dpp_add<0xB1>(d2a);
        d2b = dpp_add<0xB1>(d2b);
        d2a = dpp_add<0x4E>(d2a);
        d2b = dpp_add<0x4E>(d2b);
        d2a = dpp_add<0x141>(d2a);
        d2b = dpp_add<0x141>(d2b);

        // update replicated on all 8 lanes of the oct-group
        float zn0 = fmaf(Ar, zf0, d2a + h1r);
        float zn1 = fmaf(Ar, zf1, d2b + h1r);
        float nz0 = zn0, nz1 = zn1;
        if (zlt) {
            if (oct == 0) {
                Ob0[t * DX + z] = zn0;
                Ob1[t * DX + z] = zn1;
            }
            nz0 = (xn0 == xn0) ? fmaf(ALPHA, xn0, (1.0f - ALPHA) * zn0) : zn0;
            nz1 = (xn1 == xn1) ? fmaf(ALPHA, xn1, (1.0f - ALPHA) * zn1) : zn1;
        }
        zf0 = nz0;
        zf1 = nz1;
        if (oct == 0) { zf_s[0][z] = zf0; zf_s[1][z] = zf1; }
        __syncthreads();
    }
}

extern "C" void kernel_launch(void* const* d_in, const int* in_sizes, int n_in,
                              void* d_out, int out_size, void* d_ws, size_t ws_size,
                              hipStream_t stream) {
    const float* X  = (const float*)d_in[0];
    const float* A  = (const float*)d_in[1];
    const float* W1 = (const float*)d_in[2];
    const float* W2 = (const float*)d_in[3];
    const float* h1 = (const float*)d_in[4];
    const float* h2 = (const float*)d_in[5];
    float* out = (float*)d_out;

    plrnn_scan<<<BB / 2, 512, 0, stream>>>(X, A, W1, W2, h1, h2, out);
}

// Round 3
// 918.009 us; speedup vs baseline: 1.1713x; 1.1713x over previous
//
#include <hip/hip_runtime.h>

#define BB 512
#define TT 1024
#define DX 32
#define DZ 64
#define DY 256
#define ALPHA 0.125f
#define HP 36  // hid chunk stride: 32 floats + 4 pad (bank spread across octs)

// DPP add: x + dpp_permuted(x), VALU pipe only.
// 0xB1 = quad_perm xor1, 0x4E = quad_perm xor2, 0x141 = row_half_mirror
// (completes the 8-lane allreduce after xor1+xor2).
template<int CTRL>
__device__ __forceinline__ float dpp_add(float x) {
    int p = __builtin_amdgcn_update_dpp(0, __float_as_int(x), CTRL, 0xF, 0xF, true);
    return x + __int_as_float(p);
}

// One batch per block, 512 threads (8 waves), 512 blocks -> 2 blocks/CU
// (R2 lesson: 2 independent blocks/CU are required to hide barrier latency).
// m1: thread (y=tid>>1, half=tid&1): hidden row y over z-chunk 32*half..+31;
//     xor1 DPP completes the 64-z dot.
// m2: thread (z=tid>>3, oct=tid&7): latent row z over y-chunk 32*oct..+31;
//     xor1+xor2+half_mirror completes the 256-y dot; update fused, replicated
//     across the 8 oct lanes (oct==0 stores).
// KEY FIX vs R1: asm-pin the weight tiles in VGPRs. R1's VGPR_Count=52 proved
// the allocator rematerialized the 16 weight dwordx4 loads into EVERY step.
__global__ __launch_bounds__(512, 4)
void plrnn_scan(const float* __restrict__ X, const float* __restrict__ A,
                const float* __restrict__ W1, const float* __restrict__ W2,
                const float* __restrict__ h1, const float* __restrict__ h2,
                float* __restrict__ out) {
    const int b   = blockIdx.x;
    const int tid = threadIdx.x;

    const int y    = tid >> 1;      // m1 output row 0..255
    const int half = tid & 1;       // m1 z-chunk
    const int z    = tid >> 3;      // m2 output row 0..63
    const int oct  = tid & 7;       // m2 y-chunk
    const int wv   = tid >> 6;      // wave id 0..7

    __shared__ float zf_s[DZ];
    __shared__ float hid_s[8 * HP];

    // ---- one-time: weight tiles into registers ----
    float4 w2r[8];   // W2[y, 32*half + 4j .. +3]
    float4 w1r[8];   // W1[z, 32*oct  + 4j .. +3]
#pragma unroll
    for (int j = 0; j < 8; ++j) {
        w2r[j] = *(const float4*)&W2[y * DZ + 32 * half + 4 * j];
        w1r[j] = *(const float4*)&W1[z * DY + 32 * oct + 4 * j];
    }
    // Pin in VGPRs: asm output cannot be rematerialized from memory, so the
    // allocator must carry these 64 floats in registers across the whole loop.
#pragma unroll
    for (int j = 0; j < 8; ++j) {
        asm volatile("" : "+v"(w2r[j].x), "+v"(w2r[j].y),
                          "+v"(w2r[j].z), "+v"(w2r[j].w));
        asm volatile("" : "+v"(w1r[j].x), "+v"(w1r[j].y),
                          "+v"(w1r[j].z), "+v"(w1r[j].w));
    }

    // Fold biases into accumulator init (loop-invariant masked registers):
    // exactly one lane of each reduction group starts from the bias.
    float h2init = (half == 0) ? h2[y] : 0.0f;
    float h1init = (oct == 0) ? h1[z] : 0.0f;
    float Ar     = A[z];
    asm volatile("" : "+v"(h2init), "+v"(h1init), "+v"(Ar));

    const bool zdx = (z < DX);      // wave-uniform: z<32 <=> tid<256

    const float* xp = X   + (size_t)b * TT * DX + z;  // step offsets = immediates
    float*       op = out + (size_t)b * TT * DX + z;

    // ---- zf_0 = x0 (non-NaN) on first DX dims, else 0 (replicated per oct) ----
    float zfr = 0.0f;
    if (zdx) { float x0 = xp[0]; zfr = (x0 == x0) ? x0 : 0.0f; }
    if (oct == 0) zf_s[z] = zfr;
    __syncthreads();

    const int hidx = wv * HP + (y & 31);   // m1 write slot (half==0 lanes)

    auto step = [&](const int koff, const int pfoff) {
        // prefetch next forcing value (immediate offset; consumed at tail)
        float xnext = 0.0f;
        if (zdx) xnext = xp[pfoff];

        // ---- m1: hidden = relu(W2 @ zf + h2) ----
        const float4* zp = (const float4*)(zf_s + 32 * half);
        float a0 = h2init, a1 = 0.f, a2 = 0.f, a3 = 0.f;
#pragma unroll
        for (int j = 0; j < 8; ++j) {
            float4 v = zp[j];
            a0 = fmaf(w2r[j].x, v.x, a0);
            a1 = fmaf(w2r[j].y, v.y, a1);
            a2 = fmaf(w2r[j].z, v.z, a2);
            a3 = fmaf(w2r[j].w, v.w, a3);
        }
        float d1 = (a0 + a1) + (a2 + a3);
        d1 = dpp_add<0xB1>(d1);
        if (half == 0) hid_s[hidx] = fmaxf(d1, 0.0f);
        __syncthreads();

        // ---- m2 + fused update: z_new = A*zf + W1 @ hidden + h1 ----
        const float4* hp = (const float4*)(hid_s + HP * oct);
        float p0 = h1init, p1 = 0.f, p2 = 0.f, p3 = 0.f;
#pragma unroll
        for (int j = 0; j < 8; ++j) {
            float4 v = hp[j];
            p0 = fmaf(w1r[j].x, v.x, p0);
            p1 = fmaf(w1r[j].y, v.y, p1);
            p2 = fmaf(w1r[j].z, v.z, p2);
            p3 = fmaf(w1r[j].w, v.w, p3);
        }
        float d2 = (p0 + p1) + (p2 + p3);
        d2 = dpp_add<0xB1>(d2);
        d2 = dpp_add<0x4E>(d2);
        d2 = dpp_add<0x141>(d2);

        float zn = fmaf(Ar, zfr, d2);
        if (zdx) {                         // wave-uniform branch (waves 0-3)
            if (oct == 0) op[koff * DX] = zn;
            zfr = (xnext == xnext) ? fmaf(ALPHA, xnext, 0.875f * zn) : zn;
        } else {
            zfr = zn;
        }
        if (oct == 0) zf_s[z] = zfr;
        __syncthreads();
    };

    // main loop: 127 groups of 8 steps, prefetch offsets are immediates
    for (int tg = 0; tg < TT - 8; tg += 8) {
#pragma unroll
        for (int k = 0; k < 8; ++k) step(k, (k + 1) * DX);
        xp += 8 * DX;
        op += 8 * DX;
    }
    // peeled final group: last prefetch reads an in-bounds dummy
    // (its value only flows into zf_{T} which is never consumed)
#pragma unroll
    for (int k = 0; k < 8; ++k) step(k, (k < 7 ? (k + 1) : 7) * DX);
}

extern "C" void kernel_launch(void* const* d_in, const int* in_sizes, int n_in,
                              void* d_out, int out_size, void* d_ws, size_t ws_size,
                              hipStream_t stream) {
    const float* X  = (const float*)d_in[0];
    const float* A  = (const float*)d_in[1];
    const float* W1 = (const float*)d_in[2];
    const float* W2 = (const float*)d_in[3];
    const float* h1 = (const float*)d_in[4];
    const float* h2 = (const float*)d_in[5];
    float* out = (float*)d_out;

    plrnn_scan<<<BB, 512, 0, stream>>>(X, A, W1, W2, h1, h2, out);
}

// Round 4
// 833.739 us; speedup vs baseline: 1.2897x; 1.1011x over previous
//
#include <hip/hip_runtime.h>

#define BB 512
#define TT 1024
#define DX 32
#define DZ 64
#define DY 256
#define ALPHA 0.125f

// DPP add: x + dpp_permuted(x), VALU pipe only (folds to v_add_f32_dpp).
// 0xB1 quad_perm xor1 | 0x4E quad_perm xor2 | 0x141 row_half_mirror (8-lane)
// 0x140 row_mirror (16-lane).
template<int CTRL>
__device__ __forceinline__ float dpp_add(float x) {
    int p = __builtin_amdgcn_update_dpp(0, __float_as_int(x), CTRL, 0xF, 0xF, true);
    return x + __int_as_float(p);
}

// One batch per block, 512 threads (8 waves), 512 blocks -> 2 blocks/CU.
// R3 lesson: __launch_bounds__ min-waves only CAPS registers; the allocator
// still minimized to 52 VGPR chasing unreachable occupancy (grid gives only
// 2 blocks/CU) and rematerialized/spilled the weights each step.
// amdgpu_waves_per_eu(4,4) pins the occupancy target so the ~128-reg budget
// is actually used -> weight tiles stay resident.
// R4 restructure: register-block output rows to cut LDS-read pipe pressure
// (the co-dominant resource: R1 issued 256 ds_read_b128/CU/step):
//  m1: thread (g=tid>>3, oct=tid&7): hidden rows 4g..4g+3 over z 8*oct..+7;
//      2 ds_read_b128, 32 FMA, 8-lane DPP reduce (xor1,xor2,half_mirror) x4.
//  m2: thread (g2=tid>>4, l=tid&15): latent rows 2g2,2g2+1 over y 16l..+15;
//      4 ds_read_b128, 32 FMA, 16-lane DPP reduce (+row_mirror) x2; update
//      fused, replicated across the 16 lanes (l==0 stores).
// LDS reads/thread/step: 16 -> 6.
__global__ __launch_bounds__(512)
__attribute__((amdgpu_waves_per_eu(4, 4)))
void plrnn_scan(const float* __restrict__ X, const float* __restrict__ A,
                const float* __restrict__ W1, const float* __restrict__ W2,
                const float* __restrict__ h1, const float* __restrict__ h2,
                float* __restrict__ out) {
    const int b   = blockIdx.x;
    const int tid = threadIdx.x;

    const int g   = tid >> 3;   // m1: hidden row-group (rows 4g..4g+3)
    const int oct = tid & 7;    // m1: z-chunk 8*oct..+7
    const int g2  = tid >> 4;   // m2: latent row-pair (rows 2g2, 2g2+1)
    const int l16 = tid & 15;   // m2: y-chunk 16*l16..+15

    __shared__ float zf_s[DZ];
    __shared__ float hid_s[DY + (DY / 16) * 4];  // 16->20 stride pad (320 floats)

    // ---- one-time: weight tiles into registers ----
    float4 w2r[8];   // w2r[k].{x,y,z,w} = W2[4g+{0..3}][8*oct+k]
#pragma unroll
    for (int k = 0; k < 8; ++k) {
        const int col = 8 * oct + k;
        w2r[k] = make_float4(W2[(4 * g + 0) * DZ + col], W2[(4 * g + 1) * DZ + col],
                             W2[(4 * g + 2) * DZ + col], W2[(4 * g + 3) * DZ + col]);
    }
    float4 wa[4], wb[4];  // W1[2g2][16l..+15], W1[2g2+1][16l..+15]
#pragma unroll
    for (int j = 0; j < 4; ++j) {
        wa[j] = *(const float4*)&W1[(2 * g2 + 0) * DY + 16 * l16 + 4 * j];
        wb[j] = *(const float4*)&W1[(2 * g2 + 1) * DY + 16 * l16 + 4 * j];
    }
    // biases folded into accumulator init on exactly one lane per group
    float4 h2i = make_float4(0.f, 0.f, 0.f, 0.f);
    if (oct == 0) h2i = *(const float4*)&h2[4 * g];
    float h1a = 0.f, h1b = 0.f;
    if (l16 == 0) { h1a = h1[2 * g2]; h1b = h1[2 * g2 + 1]; }
    const float2 Av = *(const float2*)&A[2 * g2];

    // pin loop-invariants in VGPRs (budget now 128 via waves_per_eu(4,4))
#pragma unroll
    for (int k = 0; k < 8; ++k)
        asm volatile("" : "+v"(w2r[k].x), "+v"(w2r[k].y),
                          "+v"(w2r[k].z), "+v"(w2r[k].w));
#pragma unroll
    for (int j = 0; j < 4; ++j) {
        asm volatile("" : "+v"(wa[j].x), "+v"(wa[j].y), "+v"(wa[j].z), "+v"(wa[j].w));
        asm volatile("" : "+v"(wb[j].x), "+v"(wb[j].y), "+v"(wb[j].z), "+v"(wb[j].w));
    }
    asm volatile("" : "+v"(h2i.x), "+v"(h2i.y), "+v"(h2i.z), "+v"(h2i.w));

    const bool zdx = (g2 < 16);  // rows < DX; wave-uniform (tid<256)

    const float* xq = X   + (size_t)b * TT * DX + 2 * g2;  // X[t][2g2]
    float*       op = out + (size_t)b * TT * DX + 2 * g2;

    const int hwr = 4 * g + ((4 * g) >> 4) * 4;  // padded hid write index
    const int hrd = 20 * l16;                    // padded hid read base

    // ---- zf_0 = x0 (non-NaN) on first DX dims, else 0 ----
    float zf0 = 0.f, zf1 = 0.f;
    if (zdx) {
        const float2 x0 = *(const float2*)xq;
        zf0 = (x0.x == x0.x) ? x0.x : 0.f;
        zf1 = (x0.y == x0.y) ? x0.y : 0.f;
    }
    if (l16 == 0) *(float2*)&zf_s[2 * g2] = make_float2(zf0, zf1);
    __syncthreads();
    xq += DX;  // -> X[1]

    auto step = [&](const float2 xn) {
        // ---- m1: hidden rows 4g..4g+3 = relu(W2 @ zf + h2) ----
        float zl[8];
        {
            const float4* zp = (const float4*)(zf_s + 8 * oct);
            *(float4*)&zl[0] = zp[0];
            *(float4*)&zl[4] = zp[1];
        }
        float ax = h2i.x, ay = h2i.y, az = h2i.z, aw = h2i.w;
#pragma unroll
        for (int k = 0; k < 8; ++k) {
            ax = fmaf(w2r[k].x, zl[k], ax);
            ay = fmaf(w2r[k].y, zl[k], ay);
            az = fmaf(w2r[k].z, zl[k], az);
            aw = fmaf(w2r[k].w, zl[k], aw);
        }
        ax = dpp_add<0xB1>(ax); ay = dpp_add<0xB1>(ay);
        az = dpp_add<0xB1>(az); aw = dpp_add<0xB1>(aw);
        ax = dpp_add<0x4E>(ax); ay = dpp_add<0x4E>(ay);
        az = dpp_add<0x4E>(az); aw = dpp_add<0x4E>(aw);
        ax = dpp_add<0x141>(ax); ay = dpp_add<0x141>(ay);
        az = dpp_add<0x141>(az); aw = dpp_add<0x141>(aw);
        if (oct == 0)
            *(float4*)&hid_s[hwr] = make_float4(fmaxf(ax, 0.f), fmaxf(ay, 0.f),
                                                fmaxf(az, 0.f), fmaxf(aw, 0.f));
        __syncthreads();

        // ---- m2 + fused update: rows 2g2,2g2+1 of A*zf + W1@hid + h1 ----
        float hl[16];
        {
            const float4* hp = (const float4*)(hid_s + hrd);
            *(float4*)&hl[0]  = hp[0];
            *(float4*)&hl[4]  = hp[1];
            *(float4*)&hl[8]  = hp[2];
            *(float4*)&hl[12] = hp[3];
        }
        float p0 = h1a, p1 = 0.f, q0 = h1b, q1 = 0.f;
#pragma unroll
        for (int j = 0; j < 4; ++j) {
            p0 = fmaf(wa[j].x, hl[4 * j + 0], p0);
            p1 = fmaf(wa[j].y, hl[4 * j + 1], p1);
            p0 = fmaf(wa[j].z, hl[4 * j + 2], p0);
            p1 = fmaf(wa[j].w, hl[4 * j + 3], p1);
            q0 = fmaf(wb[j].x, hl[4 * j + 0], q0);
            q1 = fmaf(wb[j].y, hl[4 * j + 1], q1);
            q0 = fmaf(wb[j].z, hl[4 * j + 2], q0);
            q1 = fmaf(wb[j].w, hl[4 * j + 3], q1);
        }
        float d0 = p0 + p1, d1 = q0 + q1;
        d0 = dpp_add<0xB1>(d0);  d1 = dpp_add<0xB1>(d1);
        d0 = dpp_add<0x4E>(d0);  d1 = dpp_add<0x4E>(d1);
        d0 = dpp_add<0x141>(d0); d1 = dpp_add<0x141>(d1);
        d0 = dpp_add<0x140>(d0); d1 = dpp_add<0x140>(d1);

        const float zn0 = fmaf(Av.x, zf0, d0);
        const float zn1 = fmaf(Av.y, zf1, d1);
        if (zdx) {  // wave-uniform (waves 0-3)
            if (l16 == 0) *(float2*)op = make_float2(zn0, zn1);
            zf0 = (xn.x == xn.x) ? fmaf(ALPHA, xn.x, 0.875f * zn0) : zn0;
            zf1 = (xn.y == xn.y) ? fmaf(ALPHA, xn.y, 0.875f * zn1) : zn1;
        } else {
            zf0 = zn0;
            zf1 = zn1;
        }
        if (l16 == 0) *(float2*)&zf_s[2 * g2] = make_float2(zf0, zf1);
        __syncthreads();
    };

    for (int t = 0; t < TT - 1; ++t) {
        float2 xn = make_float2(0.f, 0.f);
        if (zdx) xn = *(const float2*)xq;   // prefetch X[t+1], consumed at tail
        xq += DX;
        step(xn);
        op += DX;
    }
    {   // last step: no next forcing value -> NaN disables the blend
        const float nanf_ = __int_as_float(0x7fc00000);
        step(make_float2(nanf_, nanf_));
    }
}

extern "C" void kernel_launch(void* const* d_in, const int* in_sizes, int n_in,
                              void* d_out, int out_size, void* d_ws, size_t ws_size,
                              hipStream_t stream) {
    const float* X  = (const float*)d_in[0];
    const float* A  = (const float*)d_in[1];
    const float* W1 = (const float*)d_in[2];
    const float* W2 = (const float*)d_in[3];
    const float* h1 = (const float*)d_in[4];
    const float* h2 = (const float*)d_in[5];
    float* out = (float*)d_out;

    plrnn_scan<<<BB, 512, 0, stream>>>(X, A, W1, W2, h1, h2, out);
}